// Round 6
// baseline (212.908 us; speedup 1.0000x reference)
//
#include <hip/hip_runtime.h>

#define HW 4096   // 64*64 pixels per (b,c) image

typedef float f4 __attribute__((ext_vector_type(4)));

// ---------------------------------------------------------------------------
// Fused proj + grid-barrier + attn.
// grid = 512 blocks x 256 thr. __launch_bounds__(256,4) caps VGPR at 128 so
// >=4 blocks/CU fit (LDS 12.7KB); we need only 2/CU resident -> 2x slack, no
// deadlock risk on the barrier. Barrier state lives in d_ws (zeroed by a
// hipMemsetAsync each launch, graph-capture-legal).
//
// Phase 1 (proj): 2048 waves; wave = 64 px (lane=px) x 24 of the 192 global
// cout-rows (q:0-63 from x, k:64-127 from x, v:128-191 from y). Lane burst-
// loads its 64-float input column once (the single x/y-straddling split
// reloads at row 128), weights stream via wave-uniform loads (scalar pipe).
// No LDS in proj: the v3/v4 LDS weight-broadcast was 2x oversubscribed.
//
// Phase 2 (attn): v4 body, 2 tasks/block (task = (b,c,16-row band)), LDS
// k/v tile with zero halo; inner op = fma + exp2 + add + fma, no clamp
// (|log2e*q*(k+bias)| < ~100 << 128, overflow impossible).
// ---------------------------------------------------------------------------
__global__ __launch_bounds__(256, 4) void fused_kernel(
    const float* __restrict__ x, const float* __restrict__ y,
    const float* __restrict__ Wq, const float* __restrict__ Wk,
    const float* __restrict__ Wv,
    const float* __restrict__ rel_h, const float* __restrict__ rel_w,
    float* __restrict__ qkv,            // q | k | v, each 1<<20 floats (d_ws)
    unsigned* __restrict__ bar,         // {cnt, flag} in d_ws, pre-zeroed
    float* __restrict__ out)
{
    __shared__ float kT[22 * 72];
    __shared__ float vT[22 * 72];

    const int t    = threadIdx.x;
    const int lane = t & 63;
    const int g    = blockIdx.x * 4 + (t >> 6);   // wave id 0..2047

    // ======================= phase 1: projections =======================
    {
        const int sp = g >> 8;             // row-split 0..7 (24 rows each)
        const int r0 = sp * 24;
        const int px = (g & 255) * 64 + lane;
        const int b  = px >> 12;
        const int pp = px & 4095;
        const bool straddle = (r0 < 128) && (r0 + 24 > 128);   // split 5 only

        float iv[64];
        {
            const float* s0 = (r0 < 128) ? x : y;
            const float* sb = s0 + (size_t)b * 64 * HW + pp;
#pragma unroll
            for (int c = 0; c < 64; ++c) iv[c] = sb[c * HW];
        }

#pragma unroll
        for (int i = 0; i < 24; ++i) {
            const int r = r0 + i;
            if (straddle && r == 128) {    // uniform branch: switch x -> y
                const float* sb = y + (size_t)b * 64 * HW + pp;
#pragma unroll
                for (int c = 0; c < 64; ++c) iv[c] = sb[c * HW];
            }
            const int m  = (r >= 64) + (r >= 128);          // 0=q 1=k 2=v
            const float* wr = (r < 64)  ? Wq + r * 64
                            : (r < 128) ? Wk + (r - 64) * 64
                                        : Wv + (r - 128) * 64;   // uniform
            float acc = 0.f;
#pragma unroll
            for (int c = 0; c < 64; ++c)
                acc = fmaf(wr[c], iv[c], acc);
            qkv[(size_t)m * (1 << 20) + ((size_t)b * 64 + (r - m * 64)) * HW + pp] = acc;
        }
    }

    // ======================= grid barrier =======================
    __syncthreads();
    if (t == 0) {
        __threadfence();                               // drain qkv stores to LLC
        const unsigned old = atomicAdd(bar, 1u);       // device-scope
        if (old == gridDim.x - 1) {
            __hip_atomic_store(bar + 1, 1u, __ATOMIC_RELEASE, __HIP_MEMORY_SCOPE_AGENT);
        } else {
            while (__hip_atomic_load(bar + 1, __ATOMIC_ACQUIRE, __HIP_MEMORY_SCOPE_AGENT) == 0u)
                __builtin_amdgcn_s_sleep(8);
        }
    }
    __syncthreads();
    __threadfence();

    // ======================= phase 2: attention =======================
    const float* qg = qkv;
    const float* kg = qkv + (1 << 20);
    const float* vg = qkv + (2 << 20);
    const f4 z4 = {0.f, 0.f, 0.f, 0.f};
    const float LOG2E = 1.4426950408889634f;

    for (int task = blockIdx.x; task < 1024; task += 512) {
        __syncthreads();                 // protect LDS reuse across tasks

        const int bc = task >> 2;        // b*64 + c
        const int h0 = (task & 3) << 4;
        const int c  = bc & 63;

        const float* kimg = kg + (size_t)bc * HW;
        const float* vimg = vg + (size_t)bc * HW;

        if (t < 88) {                    // horizontal halo zero
            const int row = t >> 2, side = (t >> 1) & 1, arr = t & 1;
            float* dst = arr ? vT : kT;
            *(f4*)&dst[row * 72 + side * 68] = z4;
        }
#pragma unroll
        for (int j = 0; j < 2; ++j) {    // interior: 22 rows x 16 f4 chunks
            const int idx = j * 256 + t;
            if (idx < 352) {
                const int row = idx >> 4, ch = idx & 15;
                const int hy = h0 - 3 + row;
                const bool rv = ((unsigned)hy < 64u);
                const f4 kv = rv ? *(const f4*)&kimg[hy * 64 + ch * 4] : z4;
                const f4 vv = rv ? *(const f4*)&vimg[hy * 64 + ch * 4] : z4;
                *(f4*)&kT[row * 72 + ch * 4 + 4] = kv;
                *(f4*)&vT[row * 72 + ch * 4 + 4] = vv;
            }
        }
        __syncthreads();

        const int r  = t >> 4;           // 0..15
        const int w0 = (t & 15) << 2;
        const int h  = h0 + r;

        const f4 qv = *(const f4*)&qg[(size_t)bc * HW + h * 64 + w0];
        float qe[4];
#pragma unroll
        for (int p = 0; p < 4; ++p) qe[p] = qv[p] * LOG2E;

        float qb[7][4];
        if (c < 32) {
#pragma unroll
            for (int a = 0; a < 7; ++a) {
                const float bb = rel_h[c * 7 + a];
#pragma unroll
                for (int p = 0; p < 4; ++p) qb[a][p] = qe[p] * bb;
            }
        } else {
#pragma unroll
            for (int j = 0; j < 7; ++j) {
                const float bb = rel_w[(c - 32) * 7 + j];
#pragma unroll
                for (int p = 0; p < 4; ++p) qb[j][p] = qe[p] * bb;
            }
        }

        float l[4] = {0.f, 0.f, 0.f, 0.f};
        float o[4] = {0.f, 0.f, 0.f, 0.f};

        if (c < 32) {
#pragma unroll
            for (int a = 0; a < 7; ++a) {
                const int ro = (r + a) * 72 + w0;
                const f4 k0 = *(const f4*)&kT[ro];
                const f4 k1 = *(const f4*)&kT[ro + 4];
                const f4 k2 = *(const f4*)&kT[ro + 8];
                const f4 v0 = *(const f4*)&vT[ro];
                const f4 v1 = *(const f4*)&vT[ro + 4];
                const f4 v2 = *(const f4*)&vT[ro + 8];
                const float kw[12] = {k0[0], k0[1], k0[2], k0[3], k1[0], k1[1], k1[2], k1[3],
                                      k2[0], k2[1], k2[2], k2[3]};
                const float vw[12] = {v0[0], v0[1], v0[2], v0[3], v1[0], v1[1], v1[2], v1[3],
                                      v2[0], v2[1], v2[2], v2[3]};
#pragma unroll
                for (int b2 = 0; b2 < 7; ++b2)
#pragma unroll
                    for (int p = 0; p < 4; ++p) {
                        const float s = fmaf(qe[p], kw[p + b2 + 1], qb[a][p]);
                        const float e = __builtin_amdgcn_exp2f(s);
                        l[p] += e;
                        o[p] = fmaf(e, vw[p + b2 + 1], o[p]);
                    }
            }
        } else {
#pragma unroll
            for (int a = 0; a < 7; ++a) {
                const int ro = (r + a) * 72 + w0;
                const f4 k0 = *(const f4*)&kT[ro];
                const f4 k1 = *(const f4*)&kT[ro + 4];
                const f4 k2 = *(const f4*)&kT[ro + 8];
                const f4 v0 = *(const f4*)&vT[ro];
                const f4 v1 = *(const f4*)&vT[ro + 4];
                const f4 v2 = *(const f4*)&vT[ro + 8];
                const float kw[12] = {k0[0], k0[1], k0[2], k0[3], k1[0], k1[1], k1[2], k1[3],
                                      k2[0], k2[1], k2[2], k2[3]};
                const float vw[12] = {v0[0], v0[1], v0[2], v0[3], v1[0], v1[1], v1[2], v1[3],
                                      v2[0], v2[1], v2[2], v2[3]};
#pragma unroll
                for (int b2 = 0; b2 < 7; ++b2)
#pragma unroll
                    for (int p = 0; p < 4; ++p) {
                        const float s = fmaf(qe[p], kw[p + b2 + 1], qb[b2][p]);
                        const float e = __builtin_amdgcn_exp2f(s);
                        l[p] += e;
                        o[p] = fmaf(e, vw[p + b2 + 1], o[p]);
                    }
            }
        }

        f4 res;
#pragma unroll
        for (int p = 0; p < 4; ++p)
            res[p] = o[p] * __builtin_amdgcn_rcpf(l[p]);
        *(f4*)&out[(size_t)bc * HW + h * 64 + w0] = res;
    }
}

// ---------------------------------------------------------------------------
extern "C" void kernel_launch(void* const* d_in, const int* in_sizes, int n_in,
                              void* d_out, int out_size, void* d_ws, size_t ws_size,
                              hipStream_t stream) {
    const float* x   = (const float*)d_in[0];
    const float* y   = (const float*)d_in[1];
    const float* Wq  = (const float*)d_in[2];
    const float* Wk  = (const float*)d_in[3];
    const float* Wv  = (const float*)d_in[4];
    const float* rlh = (const float*)d_in[5];
    const float* rlw = (const float*)d_in[6];
    float* out = (float*)d_out;

    float*    qkv = (float*)d_ws;                        // 12 MB: q|k|v
    unsigned* bar = (unsigned*)((char*)d_ws + (16u << 20));  // barrier state

    hipMemsetAsync(bar, 0, 2 * sizeof(unsigned), stream);    // capture-legal
    fused_kernel<<<512, 256, 0, stream>>>(x, y, Wq, Wk, Wv, rlh, rlw,
                                          qkv, bar, out);
}

// Round 7
// 183.397 us; speedup vs baseline: 1.1609x; 1.1609x over previous
//
#include <hip/hip_runtime.h>

#define HW 4096   // 64*64 pixels per (b,c) image

typedef float f4 __attribute__((ext_vector_type(4)));

// ---------------------------------------------------------------------------
// Fused proj + grid-barrier + attn. grid = 512 x 256 thr.
// __launch_bounds__(256,2): VGPR cap 256 -> NO SPILL (R6's VGPR=64 with
// iv[64] live proved the (256,4) cap spilled the input column to scratch ->
// 155us at VALUBusy 8%). 2 blocks/CU capacity = exactly the 512-block
// co-residency the barrier needs (actual VGPR ~75 gives ~5/CU slack).
//
// Phase 1 (proj): wave = 64 px x couts r0..r0+7 of ALL THREE matrices.
// Weight addresses derive ONLY from blockIdx + loop constants -> provably
// wave-uniform -> s_load (scalar pipe), zero VALU operand cost. Inputs
// c-blocked: xv[16]+yv[16] refilled 4x; acc[24] live. ~75 VGPR total.
// Phase 2 (attn): R6 body, 2 tasks/block, LDS k/v tile with zero halo;
// inner op = fma + exp2 + add + fma, no clamp (overflow impossible).
// ---------------------------------------------------------------------------
__global__ __launch_bounds__(256, 2) void fused_kernel(
    const float* __restrict__ x, const float* __restrict__ y,
    const float* __restrict__ Wq, const float* __restrict__ Wk,
    const float* __restrict__ Wv,
    const float* __restrict__ rel_h, const float* __restrict__ rel_w,
    float* __restrict__ qkv,            // q | k | v, each 1<<20 floats (d_ws)
    unsigned* __restrict__ bar,         // {cnt, flag} in d_ws, pre-zeroed
    float* __restrict__ out)
{
    __shared__ float kT[22 * 72];
    __shared__ float vT[22 * 72];

    const int t    = threadIdx.x;
    const int lane = t & 63;

    // ======================= phase 1: projections =======================
    {
        const int sp = blockIdx.x >> 6;              // cout-split 0..7 (UNIFORM)
        const int r0 = sp * 8;                       // couts r0..r0+7 per matrix
        const int chunk = (blockIdx.x & 63) * 4 + (t >> 6);   // px-chunk 0..255
        const int px = chunk * 64 + lane;
        const int b  = px >> 12;
        const int pp = px & 4095;
        const float* xb = x + (size_t)b * 64 * HW + pp;
        const float* yb = y + (size_t)b * 64 * HW + pp;

        float accq[8], acck[8], accv[8];
#pragma unroll
        for (int j = 0; j < 8; ++j) { accq[j] = 0.f; acck[j] = 0.f; accv[j] = 0.f; }

#pragma unroll
        for (int cb = 0; cb < 4; ++cb) {             // c-blocks of 16 channels
            float xv[16], yv[16];
#pragma unroll
            for (int c2 = 0; c2 < 16; ++c2) {
                xv[c2] = xb[(cb * 16 + c2) * HW];
                yv[c2] = yb[(cb * 16 + c2) * HW];
            }
#pragma unroll
            for (int j = 0; j < 8; ++j) {
                // blockIdx/loop-constant addresses -> s_load_dwordx16
                const float* wq = Wq + (r0 + j) * 64 + cb * 16;
                const float* wk = Wk + (r0 + j) * 64 + cb * 16;
                const float* wv = Wv + (r0 + j) * 64 + cb * 16;
#pragma unroll
                for (int c2 = 0; c2 < 16; ++c2) {
                    accq[j] = fmaf(wq[c2], xv[c2], accq[j]);
                    acck[j] = fmaf(wk[c2], xv[c2], acck[j]);
                    accv[j] = fmaf(wv[c2], yv[c2], accv[j]);
                }
            }
        }
#pragma unroll
        for (int j = 0; j < 8; ++j) {
            const size_t base = ((size_t)b * 64 + r0 + j) * HW + pp;
            qkv[base]               = accq[j];
            qkv[(1u << 20) + base]  = acck[j];
            qkv[(2u << 20) + base]  = accv[j];
        }
    }

    // ======================= grid barrier =======================
    __syncthreads();
    if (t == 0) {
        __threadfence();                               // drain qkv stores
        const unsigned old = atomicAdd(bar, 1u);       // device-scope
        if (old == gridDim.x - 1) {
            __hip_atomic_store(bar + 1, 1u, __ATOMIC_RELEASE, __HIP_MEMORY_SCOPE_AGENT);
        } else {
            while (__hip_atomic_load(bar + 1, __ATOMIC_ACQUIRE, __HIP_MEMORY_SCOPE_AGENT) == 0u)
                __builtin_amdgcn_s_sleep(8);
        }
    }
    __syncthreads();
    __threadfence();                                   // reader-side invalidate

    // ======================= phase 2: attention =======================
    const float* qg = qkv;
    const float* kg = qkv + (1 << 20);
    const float* vg = qkv + (2 << 20);
    const f4 z4 = {0.f, 0.f, 0.f, 0.f};
    const float LOG2E = 1.4426950408889634f;

    for (int task = blockIdx.x; task < 1024; task += 512) {
        __syncthreads();                 // protect LDS reuse across tasks

        const int bc = task >> 2;        // b*64 + c
        const int h0 = (task & 3) << 4;
        const int c  = bc & 63;

        const float* kimg = kg + (size_t)bc * HW;
        const float* vimg = vg + (size_t)bc * HW;

        if (t < 88) {                    // horizontal halo zero
            const int row = t >> 2, side = (t >> 1) & 1, arr = t & 1;
            float* dst = arr ? vT : kT;
            *(f4*)&dst[row * 72 + side * 68] = z4;
        }
#pragma unroll
        for (int j = 0; j < 2; ++j) {    // interior: 22 rows x 16 f4 chunks
            const int idx = j * 256 + t;
            if (idx < 352) {
                const int row = idx >> 4, ch = idx & 15;
                const int hy = h0 - 3 + row;
                const bool rv = ((unsigned)hy < 64u);
                const f4 kv = rv ? *(const f4*)&kimg[hy * 64 + ch * 4] : z4;
                const f4 vv = rv ? *(const f4*)&vimg[hy * 64 + ch * 4] : z4;
                *(f4*)&kT[row * 72 + ch * 4 + 4] = kv;
                *(f4*)&vT[row * 72 + ch * 4 + 4] = vv;
            }
        }
        __syncthreads();

        const int r  = t >> 4;           // 0..15
        const int w0 = (t & 15) << 2;
        const int h  = h0 + r;

        const f4 qv = *(const f4*)&qg[(size_t)bc * HW + h * 64 + w0];
        float qe[4];
#pragma unroll
        for (int p = 0; p < 4; ++p) qe[p] = qv[p] * LOG2E;

        float qb[7][4];
        if (c < 32) {
#pragma unroll
            for (int a = 0; a < 7; ++a) {
                const float bb = rel_h[c * 7 + a];
#pragma unroll
                for (int p = 0; p < 4; ++p) qb[a][p] = qe[p] * bb;
            }
        } else {
#pragma unroll
            for (int j = 0; j < 7; ++j) {
                const float bb = rel_w[(c - 32) * 7 + j];
#pragma unroll
                for (int p = 0; p < 4; ++p) qb[j][p] = qe[p] * bb;
            }
        }

        float l[4] = {0.f, 0.f, 0.f, 0.f};
        float o[4] = {0.f, 0.f, 0.f, 0.f};

        if (c < 32) {
#pragma unroll
            for (int a = 0; a < 7; ++a) {
                const int ro = (r + a) * 72 + w0;
                const f4 k0 = *(const f4*)&kT[ro];
                const f4 k1 = *(const f4*)&kT[ro + 4];
                const f4 k2 = *(const f4*)&kT[ro + 8];
                const f4 v0 = *(const f4*)&vT[ro];
                const f4 v1 = *(const f4*)&vT[ro + 4];
                const f4 v2 = *(const f4*)&vT[ro + 8];
                const float kw[12] = {k0[0], k0[1], k0[2], k0[3], k1[0], k1[1], k1[2], k1[3],
                                      k2[0], k2[1], k2[2], k2[3]};
                const float vw[12] = {v0[0], v0[1], v0[2], v0[3], v1[0], v1[1], v1[2], v1[3],
                                      v2[0], v2[1], v2[2], v2[3]};
#pragma unroll
                for (int b2 = 0; b2 < 7; ++b2)
#pragma unroll
                    for (int p = 0; p < 4; ++p) {
                        const float s = fmaf(qe[p], kw[p + b2 + 1], qb[a][p]);
                        const float e = __builtin_amdgcn_exp2f(s);
                        l[p] += e;
                        o[p] = fmaf(e, vw[p + b2 + 1], o[p]);
                    }
            }
        } else {
#pragma unroll
            for (int a = 0; a < 7; ++a) {
                const int ro = (r + a) * 72 + w0;
                const f4 k0 = *(const f4*)&kT[ro];
                const f4 k1 = *(const f4*)&kT[ro + 4];
                const f4 k2 = *(const f4*)&kT[ro + 8];
                const f4 v0 = *(const f4*)&vT[ro];
                const f4 v1 = *(const f4*)&vT[ro + 4];
                const f4 v2 = *(const f4*)&vT[ro + 8];
                const float kw[12] = {k0[0], k0[1], k0[2], k0[3], k1[0], k1[1], k1[2], k1[3],
                                      k2[0], k2[1], k2[2], k2[3]};
                const float vw[12] = {v0[0], v0[1], v0[2], v0[3], v1[0], v1[1], v1[2], v1[3],
                                      v2[0], v2[1], v2[2], v2[3]};
#pragma unroll
                for (int b2 = 0; b2 < 7; ++b2)
#pragma unroll
                    for (int p = 0; p < 4; ++p) {
                        const float s = fmaf(qe[p], kw[p + b2 + 1], qb[b2][p]);
                        const float e = __builtin_amdgcn_exp2f(s);
                        l[p] += e;
                        o[p] = fmaf(e, vw[p + b2 + 1], o[p]);
                    }
            }
        }

        f4 res;
#pragma unroll
        for (int p = 0; p < 4; ++p)
            res[p] = o[p] * __builtin_amdgcn_rcpf(l[p]);
        *(f4*)&out[(size_t)bc * HW + h * 64 + w0] = res;
    }
}

// ---------------------------------------------------------------------------
extern "C" void kernel_launch(void* const* d_in, const int* in_sizes, int n_in,
                              void* d_out, int out_size, void* d_ws, size_t ws_size,
                              hipStream_t stream) {
    const float* x   = (const float*)d_in[0];
    const float* y   = (const float*)d_in[1];
    const float* Wq  = (const float*)d_in[2];
    const float* Wk  = (const float*)d_in[3];
    const float* Wv  = (const float*)d_in[4];
    const float* rlh = (const float*)d_in[5];
    const float* rlw = (const float*)d_in[6];
    float* out = (float*)d_out;

    float*    qkv = (float*)d_ws;                        // 12 MB: q|k|v
    unsigned* bar = (unsigned*)((char*)d_ws + (16u << 20));  // barrier state

    hipMemsetAsync(bar, 0, 2 * sizeof(unsigned), stream);    // capture-legal
    fused_kernel<<<512, 256, 0, stream>>>(x, y, Wq, Wk, Wv, rlh, rlw,
                                          qkv, bar, out);
}

// Round 8
// 94.651 us; speedup vs baseline: 2.2494x; 1.9376x over previous
//
#include <hip/hip_runtime.h>

#define HW 4096   // 64*64 pixels per (b,c) image

typedef float f4 __attribute__((ext_vector_type(4)));
typedef float f2 __attribute__((ext_vector_type(2)));

// ---------------------------------------------------------------------------
// proj v6: q=Wq@x, k=Wk@x, v=Wv@y. grid = 768 blocks x 256 thr (3 blocks/CU,
// 3 waves/SIMD). Split sp = blockIdx>>5: 24 splits = 3 matrices x 8 row-
// groups of 8 couts — NO split straddles matrices. Thread = 2 px (f2).
// c-blocked: xv[8] f2 per 8-cin chunk; weights' addresses derive only from
// blockIdx + constants -> s_load (scalar pipe). acc[8] f2. ~50 VGPR: no
// spill (R6's VGPR=64 spill at cap 128 was the 155us disaster; R7 proved
// the c-blocked scheme fits).
// ---------------------------------------------------------------------------
__global__ __launch_bounds__(256) void proj_kernel(
    const float* __restrict__ x, const float* __restrict__ y,
    const float* __restrict__ Wq, const float* __restrict__ Wk,
    const float* __restrict__ Wv,
    float* __restrict__ qkv)     // q | k | v, each 1<<20 floats
{
    const int sp = blockIdx.x >> 5;            // 0..23 (uniform)
    const int m  = sp >> 3;                    // matrix 0=q 1=k 2=v
    const int r0 = (sp & 7) * 8;               // cout base within matrix
    const int pi = (blockIdx.x & 31) * 256 + threadIdx.x;   // px-pair 0..8191
    const int px = pi * 2;
    const int b  = px >> 12;
    const int pp = px & 4095;

    const float* W   = (m == 0) ? Wq : (m == 1) ? Wk : Wv;   // uniform
    const float* src = (m == 2) ? y : x;                     // uniform
    const float* sb  = src + (size_t)b * 64 * HW + pp;

    f2 acc[8];
#pragma unroll
    for (int j = 0; j < 8; ++j) acc[j] = (f2){0.f, 0.f};

#pragma unroll
    for (int cb = 0; cb < 8; ++cb) {           // 8 chunks of 8 input channels
        f2 xv[8];
#pragma unroll
        for (int c2 = 0; c2 < 8; ++c2)
            xv[c2] = *(const f2*)&sb[(cb * 8 + c2) * HW];
#pragma unroll
        for (int j = 0; j < 8; ++j) {
            const float* wr = W + (r0 + j) * 64 + cb * 8;    // uniform -> s_load
#pragma unroll
            for (int c2 = 0; c2 < 8; ++c2) {
                acc[j][0] = fmaf(wr[c2], xv[c2][0], acc[j][0]);
                acc[j][1] = fmaf(wr[c2], xv[c2][1], acc[j][1]);
            }
        }
    }

    float* dstm = qkv + ((size_t)m << 20) + (size_t)b * 64 * HW + pp;
#pragma unroll
    for (int j = 0; j < 8; ++j)
        *(f2*)&dstm[(size_t)(r0 + j) * HW] = acc[j];
}

// ---------------------------------------------------------------------------
// attn v5 (= R5's proven body): per-channel 7x7 window attention, LDS k/v
// tile with zero halo. Inner op: fma + exp2 + add + fma (3 VALU + 1 trans).
// No clamp: |log2e*q*(k+bias)| < ~100 << 128 -> exp2 overflow impossible.
// grid = 1024 (b, c, 16-row band), block 256, thread = 4 px.
// ---------------------------------------------------------------------------
__global__ __launch_bounds__(256) void attn_kernel(
    const float* __restrict__ qg, const float* __restrict__ kg,
    const float* __restrict__ vg,
    const float* __restrict__ rel_h, const float* __restrict__ rel_w,
    float* __restrict__ out)
{
    __shared__ float kT[22 * 72];
    __shared__ float vT[22 * 72];

    const int blk = blockIdx.x;
    const int bc  = blk >> 2;            // b*64 + c
    const int h0  = (blk & 3) << 4;
    const int c   = bc & 63;
    const int t   = threadIdx.x;

    const float* kimg = kg + (size_t)bc * HW;
    const float* vimg = vg + (size_t)bc * HW;
    const f4 z4 = {0.f, 0.f, 0.f, 0.f};

    if (t < 88) {                        // horizontal halo zero
        const int row = t >> 2, side = (t >> 1) & 1, arr = t & 1;
        float* dst = arr ? vT : kT;
        *(f4*)&dst[row * 72 + side * 68] = z4;
    }
#pragma unroll
    for (int j = 0; j < 2; ++j) {        // interior: 22 rows x 16 f4 chunks
        const int idx = j * 256 + t;
        if (idx < 352) {
            const int row = idx >> 4, ch = idx & 15;
            const int hy = h0 - 3 + row;
            const bool rv = ((unsigned)hy < 64u);
            const f4 kv = rv ? *(const f4*)&kimg[hy * 64 + ch * 4] : z4;
            const f4 vv = rv ? *(const f4*)&vimg[hy * 64 + ch * 4] : z4;
            *(f4*)&kT[row * 72 + ch * 4 + 4] = kv;
            *(f4*)&vT[row * 72 + ch * 4 + 4] = vv;
        }
    }
    __syncthreads();

    const int r  = t >> 4;               // 0..15
    const int w0 = (t & 15) << 2;
    const int h  = h0 + r;

    const float LOG2E = 1.4426950408889634f;
    const f4 qv = *(const f4*)&qg[(size_t)bc * HW + h * 64 + w0];
    float qe[4];
#pragma unroll
    for (int p = 0; p < 4; ++p) qe[p] = qv[p] * LOG2E;

    float qb[7][4];
    if (c < 32) {
#pragma unroll
        for (int a = 0; a < 7; ++a) {
            const float bb = rel_h[c * 7 + a];
#pragma unroll
            for (int p = 0; p < 4; ++p) qb[a][p] = qe[p] * bb;
        }
    } else {
#pragma unroll
        for (int j = 0; j < 7; ++j) {
            const float bb = rel_w[(c - 32) * 7 + j];
#pragma unroll
            for (int p = 0; p < 4; ++p) qb[j][p] = qe[p] * bb;
        }
    }

    float l[4] = {0.f, 0.f, 0.f, 0.f};
    float o[4] = {0.f, 0.f, 0.f, 0.f};

    if (c < 32) {
#pragma unroll
        for (int a = 0; a < 7; ++a) {
            const int ro = (r + a) * 72 + w0;
            const f4 k0 = *(const f4*)&kT[ro];
            const f4 k1 = *(const f4*)&kT[ro + 4];
            const f4 k2 = *(const f4*)&kT[ro + 8];
            const f4 v0 = *(const f4*)&vT[ro];
            const f4 v1 = *(const f4*)&vT[ro + 4];
            const f4 v2 = *(const f4*)&vT[ro + 8];
            const float kw[12] = {k0[0], k0[1], k0[2], k0[3], k1[0], k1[1], k1[2], k1[3],
                                  k2[0], k2[1], k2[2], k2[3]};
            const float vw[12] = {v0[0], v0[1], v0[2], v0[3], v1[0], v1[1], v1[2], v1[3],
                                  v2[0], v2[1], v2[2], v2[3]};
#pragma unroll
            for (int b2 = 0; b2 < 7; ++b2)
#pragma unroll
                for (int p = 0; p < 4; ++p) {
                    const float s = fmaf(qe[p], kw[p + b2 + 1], qb[a][p]);
                    const float e = __builtin_amdgcn_exp2f(s);
                    l[p] += e;
                    o[p] = fmaf(e, vw[p + b2 + 1], o[p]);
                }
        }
    } else {
#pragma unroll
        for (int a = 0; a < 7; ++a) {
            const int ro = (r + a) * 72 + w0;
            const f4 k0 = *(const f4*)&kT[ro];
            const f4 k1 = *(const f4*)&kT[ro + 4];
            const f4 k2 = *(const f4*)&kT[ro + 8];
            const f4 v0 = *(const f4*)&vT[ro];
            const f4 v1 = *(const f4*)&vT[ro + 4];
            const f4 v2 = *(const f4*)&vT[ro + 8];
            const float kw[12] = {k0[0], k0[1], k0[2], k0[3], k1[0], k1[1], k1[2], k1[3],
                                  k2[0], k2[1], k2[2], k2[3]};
            const float vw[12] = {v0[0], v0[1], v0[2], v0[3], v1[0], v1[1], v1[2], v1[3],
                                  v2[0], v2[1], v2[2], v2[3]};
#pragma unroll
            for (int b2 = 0; b2 < 7; ++b2)
#pragma unroll
                for (int p = 0; p < 4; ++p) {
                    const float s = fmaf(qe[p], kw[p + b2 + 1], qb[b2][p]);
                    const float e = __builtin_amdgcn_exp2f(s);
                    l[p] += e;
                    o[p] = fmaf(e, vw[p + b2 + 1], o[p]);
                }
        }
    }

    f4 res;
#pragma unroll
    for (int p = 0; p < 4; ++p)
        res[p] = o[p] * __builtin_amdgcn_rcpf(l[p]);
    *(f4*)&out[(size_t)bc * HW + h * 64 + w0] = res;
}

// ---------------------------------------------------------------------------
extern "C" void kernel_launch(void* const* d_in, const int* in_sizes, int n_in,
                              void* d_out, int out_size, void* d_ws, size_t ws_size,
                              hipStream_t stream) {
    const float* x   = (const float*)d_in[0];
    const float* y   = (const float*)d_in[1];
    const float* Wq  = (const float*)d_in[2];
    const float* Wk  = (const float*)d_in[3];
    const float* Wv  = (const float*)d_in[4];
    const float* rlh = (const float*)d_in[5];
    const float* rlw = (const float*)d_in[6];
    float* out = (float*)d_out;

    float* qkv = (float*)d_ws;        // q | k | v, 4 MB each, contiguous
    float* q = qkv;
    float* k = qkv + (1 << 20);
    float* v = qkv + (2 << 20);

    proj_kernel<<<768, 256, 0, stream>>>(x, y, Wq, Wk, Wv, qkv);
    attn_kernel<<<1024, 256, 0, stream>>>(q, k, v, rlh, rlw, out);
}